// Round 1
// baseline (1305.814 us; speedup 1.0000x reference)
//
#include <hip/hip_runtime.h>

typedef unsigned short u16;
typedef __attribute__((ext_vector_type(8))) short bf16x8;
typedef __attribute__((ext_vector_type(4))) float f32x4;

#define S_LEN 2048
#define D_MODEL 2048
#define NHEAD 32
#define DHEAD 64
#define FF_DIM 8192
#define NTOK 4096
#define BK 64

__device__ __forceinline__ u16 f2bf(float f) {
  union { float f; unsigned u; } v; v.f = f;
  unsigned r = v.u + 0x7fffu + ((v.u >> 16) & 1u);
  return (u16)(r >> 16);
}
__device__ __forceinline__ float bf2f(u16 b) {
  union { unsigned u; float f; } v; v.u = ((unsigned)b) << 16;
  return v.f;
}
__device__ __forceinline__ void gload_lds16(const void* g, void* l) {
  __builtin_amdgcn_global_load_lds(
      (const __attribute__((address_space(1))) void*)g,
      (__attribute__((address_space(3))) void*)l, 16, 0, 0);
}

// ---------------- weight transpose + f32->bf16 convert ----------------
// in: [Kd][Nd] f32 row-major; out: [Nd][Kd] bf16 row-major
__global__ __launch_bounds__(256) void wconv_kernel(
    const float* __restrict__ in, u16* __restrict__ out, int Kd, int Nd) {
  __shared__ float tile[64][65];
  const int n0 = blockIdx.x * 64, k0 = blockIdx.y * 64;
  const int tid = threadIdx.x;
  const int r = tid >> 4, c4 = (tid & 15) * 4;
#pragma unroll
  for (int rr = 0; rr < 4; ++rr) {
    int kr = rr * 16 + r;
    float4 v = *(const float4*)&in[(size_t)(k0 + kr) * Nd + n0 + c4];
    tile[kr][c4 + 0] = v.x; tile[kr][c4 + 1] = v.y;
    tile[kr][c4 + 2] = v.z; tile[kr][c4 + 3] = v.w;
  }
  __syncthreads();
#pragma unroll
  for (int rr = 0; rr < 4; ++rr) {
    int nr = rr * 16 + r;
    uint2 o;
    o.x = (unsigned)f2bf(tile[c4 + 0][nr]) | ((unsigned)f2bf(tile[c4 + 1][nr]) << 16);
    o.y = (unsigned)f2bf(tile[c4 + 2][nr]) | ((unsigned)f2bf(tile[c4 + 3][nr]) << 16);
    *(uint2*)&out[(size_t)(n0 + nr) * Kd + k0 + c4] = o;
  }
}

// ---------------- RMSNorm: f32 in -> bf16 out ----------------
__global__ __launch_bounds__(256) void rmsnorm_kernel(
    const float* __restrict__ in, const float* __restrict__ wt, u16* __restrict__ out) {
  const int row = blockIdx.x;
  const int tid = threadIdx.x;
  const float* rp = in + (size_t)row * D_MODEL;
  float4 a = *(const float4*)&rp[tid * 8];
  float4 b = *(const float4*)&rp[tid * 8 + 4];
  float ss = a.x*a.x + a.y*a.y + a.z*a.z + a.w*a.w
           + b.x*b.x + b.y*b.y + b.z*b.z + b.w*b.w;
#pragma unroll
  for (int d = 1; d < 64; d <<= 1) ss += __shfl_xor(ss, d);
  __shared__ float red[4];
  if ((tid & 63) == 0) red[tid >> 6] = ss;
  __syncthreads();
  float tot = red[0] + red[1] + red[2] + red[3];
  float rms = rsqrtf(tot * (1.f / (float)D_MODEL) + 1e-6f);
  float4 wa = *(const float4*)&wt[tid * 8];
  float4 wb = *(const float4*)&wt[tid * 8 + 4];
  uint4 o;
  o.x = (unsigned)f2bf(a.x * rms * wa.x) | ((unsigned)f2bf(a.y * rms * wa.y) << 16);
  o.y = (unsigned)f2bf(a.z * rms * wa.z) | ((unsigned)f2bf(a.w * rms * wa.w) << 16);
  o.z = (unsigned)f2bf(b.x * rms * wb.x) | ((unsigned)f2bf(b.y * rms * wb.y) << 16);
  o.w = (unsigned)f2bf(b.z * rms * wb.z) | ((unsigned)f2bf(b.w * rms * wb.w) << 16);
  *(uint4*)&out[(size_t)row * D_MODEL + tid * 8] = o;
}

// ---------------- RoPE in-place on q,k (bf16) ----------------
__global__ __launch_bounds__(256) void rope_kernel(
    u16* __restrict__ q, u16* __restrict__ k,
    const float* __restrict__ fc, const float* __restrict__ fs) {
  const int idx = blockIdx.x * 256 + threadIdx.x;   // over NTOK*1024 pairs
  u16* t = blockIdx.y ? k : q;
  const int p = idx & 1023;       // h*32 + i
  const int i = p & 31;
  const int tok = idx >> 10;
  const int s = tok & (S_LEN - 1);
  unsigned u = ((unsigned*)t)[idx];
  float v0 = bf2f((u16)(u & 0xffff));
  float v1 = bf2f((u16)(u >> 16));
  float c = fc[s * 32 + i], sn = fs[s * 32 + i];
  float r0 = v0 * c - v1 * sn;
  float r1 = v0 * sn + v1 * c;
  ((unsigned*)t)[idx] = (unsigned)f2bf(r0) | ((unsigned)f2bf(r1) << 16);
}

// ---------------- GEMM: C[M][N] = A[M][K] (bf16) @ Bt[N][K]^T (bf16) ----------------
// EPI: 0 = bf16 store; 1 = bf16 store transposed-per-head (V->vt[bh][dh][s]);
//      2 = f32 store out = xres + acc; 3 = f32 out += acc;
//      4 = bf16 store silu(gate)*acc (gate read from `gate`, write to `obf`)
template <int EPI>
__global__ __launch_bounds__(256) void gemm_bt(
    const u16* __restrict__ A, const u16* __restrict__ Bt,
    int M, int N, int K,
    u16* obf, float* ofl, const float* __restrict__ xres, const u16* gate) {
  __shared__ u16 lA[128 * BK];
  __shared__ u16 lB[128 * BK];
  const int tid = threadIdx.x;
  const int w = tid >> 6, lane = tid & 63;
  const int m0 = blockIdx.x * 128, n0 = blockIdx.y * 128;
  const int wm = (w >> 1) * 64, wn = (w & 1) * 64;
  const int row_l = lane >> 3;          // 0..7
  const int kofs_l = (lane & 7) * 8;    // elems
  f32x4 acc[4][4] = {};
  for (int kt = 0; kt < K; kt += BK) {
#pragma unroll
    for (int it = 0; it < 4; ++it) {
      int r = it * 32 + w * 8 + row_l;
      gload_lds16(A + (size_t)(m0 + r) * K + kt + kofs_l, &lA[(it * 32 + w * 8) * BK]);
      gload_lds16(Bt + (size_t)(n0 + r) * K + kt + kofs_l, &lB[(it * 32 + w * 8) * BK]);
    }
    __syncthreads();
#pragma unroll
    for (int kk = 0; kk < BK; kk += 32) {
      bf16x8 af[4], bfr[4];
#pragma unroll
      for (int i = 0; i < 4; ++i)
        af[i] = *(const bf16x8*)&lA[(wm + i * 16 + (lane & 15)) * BK + kk + (lane >> 4) * 8];
#pragma unroll
      for (int j = 0; j < 4; ++j)
        bfr[j] = *(const bf16x8*)&lB[(wn + j * 16 + (lane & 15)) * BK + kk + (lane >> 4) * 8];
#pragma unroll
      for (int i = 0; i < 4; ++i)
#pragma unroll
        for (int j = 0; j < 4; ++j)
          acc[i][j] = __builtin_amdgcn_mfma_f32_16x16x32_bf16(af[i], bfr[j], acc[i][j], 0, 0, 0);
    }
    __syncthreads();
  }
  const int rbase = (lane >> 4) * 4;
  const int cl = lane & 15;
#pragma unroll
  for (int i = 0; i < 4; ++i) {
#pragma unroll
    for (int r = 0; r < 4; ++r) {
      int grow = m0 + wm + i * 16 + rbase + r;
#pragma unroll
      for (int j = 0; j < 4; ++j) {
        int gcol = n0 + wn + j * 16 + cl;
        float v = acc[i][j][r];
        if (EPI == 0) {
          obf[(size_t)grow * N + gcol] = f2bf(v);
        } else if (EPI == 1) {
          int b = grow >> 11, s = grow & (S_LEN - 1);
          int h = gcol >> 6, dh = gcol & 63;
          obf[((((size_t)b * NHEAD + h) * DHEAD + dh) << 11) + s] = f2bf(v);
        } else if (EPI == 2) {
          ofl[(size_t)grow * N + gcol] = xres[(size_t)grow * N + gcol] + v;
        } else if (EPI == 3) {
          ofl[(size_t)grow * N + gcol] += v;
        } else if (EPI == 4) {
          float g = bf2f(gate[(size_t)grow * N + gcol]);
          float sg = g / (1.f + __expf(-g));
          obf[(size_t)grow * N + gcol] = f2bf(sg * v);
        }
      }
    }
  }
}

// ---------------- Flash attention (causal) ----------------
// q,k: [NTOK][D_MODEL] bf16 (post-rope); vt: [B*NHEAD][DHEAD][S_LEN] bf16
// o: [NTOK][D_MODEL] bf16
__global__ __launch_bounds__(256) void attn_kernel(
    const u16* __restrict__ q, const u16* __restrict__ k,
    const u16* __restrict__ vt, u16* __restrict__ o) {
  __shared__ u16 lK[64 * 64];
  __shared__ u16 lV[64 * 64];
  __shared__ u16 lP[4][16 * 64];
  const int tid = threadIdx.x, w = tid >> 6, lane = tid & 63;
  const int bx = blockIdx.x;        // q tile (32)
  const int bh = blockIdx.y;        // b*NHEAD + h (64)
  const int b = bh >> 5, h = bh & 31;
  const int q0 = bx * 64;
  const int ql = lane & 15;
  const int rbase = (lane >> 4) * 4;
  const int row_l = lane >> 3, kofs_l = (lane & 7) * 8;

  bf16x8 qf[2];
  {
    size_t tok = (size_t)b * S_LEN + q0 + w * 16 + ql;
#pragma unroll
    for (int kk = 0; kk < 2; ++kk)
      qf[kk] = *(const bf16x8*)&q[tok * D_MODEL + h * DHEAD + kk * 32 + (lane >> 4) * 8];
  }
  float mrow[4], lrow[4];
  f32x4 oacc[4] = {};
#pragma unroll
  for (int r = 0; r < 4; ++r) { mrow[r] = -1e30f; lrow[r] = 0.f; }

  for (int kt = 0; kt <= bx; ++kt) {
    const int s0 = kt * 64;
#pragma unroll
    for (int it = 0; it < 2; ++it) {
      int r = it * 32 + w * 8 + row_l;
      gload_lds16(&k[((size_t)b * S_LEN + s0 + r) * D_MODEL + h * DHEAD + kofs_l],
                  &lK[(it * 32 + w * 8) * 64]);
      gload_lds16(&vt[((size_t)bh * DHEAD + r) * S_LEN + s0 + kofs_l],
                  &lV[(it * 32 + w * 8) * 64]);
    }
    __syncthreads();
    f32x4 sc[4] = {};
#pragma unroll
    for (int kk = 0; kk < 2; ++kk) {
#pragma unroll
      for (int j = 0; j < 4; ++j) {
        bf16x8 bk = *(const bf16x8*)&lK[(j * 16 + ql) * 64 + kk * 32 + (lane >> 4) * 8];
        sc[j] = __builtin_amdgcn_mfma_f32_16x16x32_bf16(qf[kk], bk, sc[j], 0, 0, 0);
      }
    }
    const bool diag = (kt == bx);
#pragma unroll
    for (int j = 0; j < 4; ++j) {
#pragma unroll
      for (int r = 0; r < 4; ++r) {
        float v = sc[j][r] * 0.125f;
        if (diag) {
          int col = s0 + j * 16 + ql;
          int row = q0 + w * 16 + rbase + r;
          if (col > row) v = -1e30f;
        }
        sc[j][r] = v;
      }
    }
    float alpha[4];
#pragma unroll
    for (int r = 0; r < 4; ++r) {
      float mx = fmaxf(fmaxf(sc[0][r], sc[1][r]), fmaxf(sc[2][r], sc[3][r]));
#pragma unroll
      for (int d = 1; d < 16; d <<= 1) mx = fmaxf(mx, __shfl_xor(mx, d));
      float mnew = fmaxf(mrow[r], mx);
      alpha[r] = __expf(mrow[r] - mnew);
      mrow[r] = mnew;
      float rs = 0.f;
#pragma unroll
      for (int j = 0; j < 4; ++j) {
        float p = __expf(sc[j][r] - mnew);
        sc[j][r] = p;
        rs += p;
      }
#pragma unroll
      for (int d = 1; d < 16; d <<= 1) rs += __shfl_xor(rs, d);
      lrow[r] = lrow[r] * alpha[r] + rs;
    }
#pragma unroll
    for (int j = 0; j < 4; ++j)
#pragma unroll
      for (int r = 0; r < 4; ++r)
        oacc[j][r] *= alpha[r];
#pragma unroll
    for (int j = 0; j < 4; ++j)
#pragma unroll
      for (int r = 0; r < 4; ++r)
        lP[w][(rbase + r) * 64 + j * 16 + ql] = f2bf(sc[j][r]);
#pragma unroll
    for (int kk = 0; kk < 2; ++kk) {
      bf16x8 pa = *(const bf16x8*)&lP[w][ql * 64 + kk * 32 + (lane >> 4) * 8];
#pragma unroll
      for (int j = 0; j < 4; ++j) {
        bf16x8 bv = *(const bf16x8*)&lV[(j * 16 + ql) * 64 + kk * 32 + (lane >> 4) * 8];
        oacc[j] = __builtin_amdgcn_mfma_f32_16x16x32_bf16(pa, bv, oacc[j], 0, 0, 0);
      }
    }
    __syncthreads();
  }
#pragma unroll
  for (int r = 0; r < 4; ++r) {
    float inv = 1.f / lrow[r];
    size_t tok = (size_t)b * S_LEN + q0 + w * 16 + rbase + r;
#pragma unroll
    for (int j = 0; j < 4; ++j)
      o[tok * D_MODEL + h * DHEAD + j * 16 + ql] = f2bf(oacc[j][r] * inv);
  }
}

// ---------------- host ----------------
extern "C" void kernel_launch(void* const* d_in, const int* in_sizes, int n_in,
                              void* d_out, int out_size, void* d_ws, size_t ws_size,
                              hipStream_t stream) {
  (void)in_sizes; (void)n_in; (void)out_size; (void)ws_size;
  const float* x  = (const float*)d_in[0];
  const float* fc = (const float*)d_in[1];
  const float* fs = (const float*)d_in[2];
  const float* wq = (const float*)d_in[4];
  const float* wk = (const float*)d_in[5];
  const float* wv = (const float*)d_in[6];
  const float* wo = (const float*)d_in[7];
  const float* wg = (const float*)d_in[8];
  const float* wu = (const float*)d_in[9];
  const float* wd = (const float*)d_in[10];
  const float* n1 = (const float*)d_in[11];
  const float* n2 = (const float*)d_in[12];
  float* out = (float*)d_out;

  char* ws = (char*)d_ws;
  size_t off = 0;
  auto alloc = [&](size_t bytes) { void* p = ws + off; off += (bytes + 255) & ~(size_t)255; return p; };
  u16* wq_t = (u16*)alloc((size_t)D_MODEL * D_MODEL * 2);
  u16* wk_t = (u16*)alloc((size_t)D_MODEL * D_MODEL * 2);
  u16* wv_t = (u16*)alloc((size_t)D_MODEL * D_MODEL * 2);
  u16* wo_t = (u16*)alloc((size_t)D_MODEL * D_MODEL * 2);
  u16* wg_t = (u16*)alloc((size_t)D_MODEL * FF_DIM * 2);
  u16* wu_t = (u16*)alloc((size_t)D_MODEL * FF_DIM * 2);
  u16* wd_t = (u16*)alloc((size_t)FF_DIM * D_MODEL * 2);
  u16* hn   = (u16*)alloc((size_t)NTOK * D_MODEL * 2);
  u16* qb   = (u16*)alloc((size_t)NTOK * D_MODEL * 2);
  u16* kb   = (u16*)alloc((size_t)NTOK * D_MODEL * 2);
  u16* vtb  = (u16*)alloc((size_t)NTOK * D_MODEL * 2);
  u16* ao   = (u16*)alloc((size_t)NTOK * D_MODEL * 2);
  u16* gt   = (u16*)alloc((size_t)NTOK * FF_DIM * 2);

  // 1. weight convert+transpose
  wconv_kernel<<<dim3(32, 32), 256, 0, stream>>>(wq, wq_t, D_MODEL, D_MODEL);
  wconv_kernel<<<dim3(32, 32), 256, 0, stream>>>(wk, wk_t, D_MODEL, D_MODEL);
  wconv_kernel<<<dim3(32, 32), 256, 0, stream>>>(wv, wv_t, D_MODEL, D_MODEL);
  wconv_kernel<<<dim3(32, 32), 256, 0, stream>>>(wo, wo_t, D_MODEL, D_MODEL);
  wconv_kernel<<<dim3(FF_DIM / 64, 32), 256, 0, stream>>>(wg, wg_t, D_MODEL, FF_DIM);
  wconv_kernel<<<dim3(FF_DIM / 64, 32), 256, 0, stream>>>(wu, wu_t, D_MODEL, FF_DIM);
  wconv_kernel<<<dim3(32, FF_DIM / 64), 256, 0, stream>>>(wd, wd_t, FF_DIM, D_MODEL);
  // 2. rmsnorm1: x -> hn (bf16)
  rmsnorm_kernel<<<NTOK, 256, 0, stream>>>(x, n1, hn);
  // 3. QKV
  gemm_bt<0><<<dim3(32, 16), 256, 0, stream>>>(hn, wq_t, NTOK, D_MODEL, D_MODEL, qb, nullptr, nullptr, nullptr);
  gemm_bt<0><<<dim3(32, 16), 256, 0, stream>>>(hn, wk_t, NTOK, D_MODEL, D_MODEL, kb, nullptr, nullptr, nullptr);
  gemm_bt<1><<<dim3(32, 16), 256, 0, stream>>>(hn, wv_t, NTOK, D_MODEL, D_MODEL, vtb, nullptr, nullptr, nullptr);
  // 4. RoPE on q,k
  rope_kernel<<<dim3(NTOK * 1024 / 256, 2), 256, 0, stream>>>(qb, kb, fc, fs);
  // 5. attention
  attn_kernel<<<dim3(32, 64), 256, 0, stream>>>(qb, kb, vtb, ao);
  // 6. O proj + residual -> d_out (f32 h)
  gemm_bt<2><<<dim3(32, 16), 256, 0, stream>>>(ao, wo_t, NTOK, D_MODEL, D_MODEL, nullptr, out, x, nullptr);
  // 7. rmsnorm2: h -> g (reuse hn)
  rmsnorm_kernel<<<NTOK, 256, 0, stream>>>(out, n2, hn);
  // 8. gate
  gemm_bt<0><<<dim3(32, 64), 256, 0, stream>>>(hn, wg_t, NTOK, FF_DIM, D_MODEL, gt, nullptr, nullptr, nullptr);
  // 9. up with fused silu(gate)*up -> gt
  gemm_bt<4><<<dim3(32, 64), 256, 0, stream>>>(hn, wu_t, NTOK, FF_DIM, D_MODEL, gt, nullptr, nullptr, gt);
  // 10. down, += into d_out
  gemm_bt<3><<<dim3(32, 16), 256, 0, stream>>>(gt, wd_t, NTOK, D_MODEL, FF_DIM, nullptr, out, nullptr, nullptr);
}

// Round 2
// 1056.026 us; speedup vs baseline: 1.2365x; 1.2365x over previous
//
#include <hip/hip_runtime.h>

typedef unsigned short u16;
typedef __attribute__((ext_vector_type(8))) short bf16x8;
typedef __attribute__((ext_vector_type(4))) float f32x4;

#define S_LEN 2048
#define D_MODEL 2048
#define NHEAD 32
#define DHEAD 64
#define FF_DIM 8192
#define NTOK 4096

// GEMM geometry: BM=256, BN=128, BK=64, 8 waves (4M x 2N), ring-3 LDS
#define GBM 256
#define GBN 128
#define GBK 64
#define SLOT_U16 (GBM * GBK + GBN * GBK)   // 16384 + 8192 = 24576 u16 = 48KB
#define GEMM_LDS_BYTES (3 * SLOT_U16 * 2)  // 144KB

__device__ __forceinline__ u16 f2bf(float f) {
  union { float f; unsigned u; } v; v.f = f;
  unsigned r = v.u + 0x7fffu + ((v.u >> 16) & 1u);
  return (u16)(r >> 16);
}
__device__ __forceinline__ float bf2f(u16 b) {
  union { unsigned u; float f; } v; v.u = ((unsigned)b) << 16;
  return v.f;
}
__device__ __forceinline__ void gload_lds16(const void* g, void* l) {
  __builtin_amdgcn_global_load_lds(
      (const __attribute__((address_space(1))) void*)g,
      (__attribute__((address_space(3))) void*)l, 16, 0, 0);
}

// ---------------- weight transpose + f32->bf16 convert ----------------
__global__ __launch_bounds__(256) void wconv_kernel(
    const float* __restrict__ in, u16* __restrict__ out, int Kd, int Nd) {
  __shared__ float tile[64][65];
  const int n0 = blockIdx.x * 64, k0 = blockIdx.y * 64;
  const int tid = threadIdx.x;
  const int r = tid >> 4, c4 = (tid & 15) * 4;
#pragma unroll
  for (int rr = 0; rr < 4; ++rr) {
    int kr = rr * 16 + r;
    float4 v = *(const float4*)&in[(size_t)(k0 + kr) * Nd + n0 + c4];
    tile[kr][c4 + 0] = v.x; tile[kr][c4 + 1] = v.y;
    tile[kr][c4 + 2] = v.z; tile[kr][c4 + 3] = v.w;
  }
  __syncthreads();
#pragma unroll
  for (int rr = 0; rr < 4; ++rr) {
    int nr = rr * 16 + r;
    uint2 o;
    o.x = (unsigned)f2bf(tile[c4 + 0][nr]) | ((unsigned)f2bf(tile[c4 + 1][nr]) << 16);
    o.y = (unsigned)f2bf(tile[c4 + 2][nr]) | ((unsigned)f2bf(tile[c4 + 3][nr]) << 16);
    *(uint2*)&out[(size_t)(n0 + nr) * Kd + k0 + c4] = o;
  }
}

// ---------------- RMSNorm: f32 in -> bf16 out ----------------
__global__ __launch_bounds__(256) void rmsnorm_kernel(
    const float* __restrict__ in, const float* __restrict__ wt, u16* __restrict__ out) {
  const int row = blockIdx.x;
  const int tid = threadIdx.x;
  const float* rp = in + (size_t)row * D_MODEL;
  float4 a = *(const float4*)&rp[tid * 8];
  float4 b = *(const float4*)&rp[tid * 8 + 4];
  float ss = a.x*a.x + a.y*a.y + a.z*a.z + a.w*a.w
           + b.x*b.x + b.y*b.y + b.z*b.z + b.w*b.w;
#pragma unroll
  for (int d = 1; d < 64; d <<= 1) ss += __shfl_xor(ss, d);
  __shared__ float red[4];
  if ((tid & 63) == 0) red[tid >> 6] = ss;
  __syncthreads();
  float tot = red[0] + red[1] + red[2] + red[3];
  float rms = rsqrtf(tot * (1.f / (float)D_MODEL) + 1e-6f);
  float4 wa = *(const float4*)&wt[tid * 8];
  float4 wb = *(const float4*)&wt[tid * 8 + 4];
  uint4 o;
  o.x = (unsigned)f2bf(a.x * rms * wa.x) | ((unsigned)f2bf(a.y * rms * wa.y) << 16);
  o.y = (unsigned)f2bf(a.z * rms * wa.z) | ((unsigned)f2bf(a.w * rms * wa.w) << 16);
  o.z = (unsigned)f2bf(b.x * rms * wb.x) | ((unsigned)f2bf(b.y * rms * wb.y) << 16);
  o.w = (unsigned)f2bf(b.z * rms * wb.z) | ((unsigned)f2bf(b.w * rms * wb.w) << 16);
  *(uint4*)&out[(size_t)row * D_MODEL + tid * 8] = o;
}

// ---------------- RoPE in-place on q,k (bf16) ----------------
__global__ __launch_bounds__(256) void rope_kernel(
    u16* __restrict__ q, u16* __restrict__ k,
    const float* __restrict__ fc, const float* __restrict__ fs) {
  const int idx = blockIdx.x * 256 + threadIdx.x;   // over NTOK*1024 pairs
  u16* t = blockIdx.y ? k : q;
  const int p = idx & 1023;
  const int i = p & 31;
  const int tok = idx >> 10;
  const int s = tok & (S_LEN - 1);
  unsigned u = ((unsigned*)t)[idx];
  float v0 = bf2f((u16)(u & 0xffff));
  float v1 = bf2f((u16)(u >> 16));
  float c = fc[s * 32 + i], sn = fs[s * 32 + i];
  float r0 = v0 * c - v1 * sn;
  float r1 = v0 * sn + v1 * c;
  ((unsigned*)t)[idx] = (unsigned)f2bf(r0) | ((unsigned)f2bf(r1) << 16);
}

// ---------------- stage one operand tile (RN rows x 64 K) into a ring slot ----------------
// Linear LDS dest (global_load_lds requirement); swizzle pre-applied to the
// per-lane GLOBAL source address (involution: byte ^= ((row&7)<<4)).
template <int RN>
__device__ __forceinline__ void stage_op(const u16* src, int Kelems,
                                         int row0, int ktbyte, u16* slot,
                                         int w, int lane) {
  constexpr int L = RN / 64;  // load rounds per thread (A:4, B:2)
#pragma unroll
  for (int l = 0; l < L; ++l) {
    const int dst = l * 8192 + w * 1024;          // wave-uniform dest byte
    const int dl = dst + lane * 16;               // this lane's dest byte
    const int srcb = dl ^ (((dl >> 7) & 7) << 4); // swizzled logical byte
    const int row = srcb >> 7, colb = srcb & 127;
    gload_lds16((const char*)src + (size_t)(row0 + row) * Kelems * 2 + ktbyte + colb,
                (char*)slot + dst);
  }
}

// ---------------- GEMM core: ring-3, counted vmcnt, swizzled LDS ----------------
// C[M][N] = A[M][K] (bf16) @ Bt[N][K]^T (bf16)
// EPI: 0 bf16 store; 1 bf16 store V-head-transposed; 2 f32 out = xres + acc;
//      3 f32 out += acc; 4 bf16 store silu(gate)*acc
template <int EPI>
__global__ __launch_bounds__(512, 2) void gemm3(
    const u16* __restrict__ A, const u16* __restrict__ Bt,
    int M, int N, int K,
    u16* obf, float* ofl, const float* __restrict__ xres, const u16* gate) {
  extern __shared__ u16 smem[];
  const int tid = threadIdx.x;
  const int w = tid >> 6, lane = tid & 63;
  // XCD-bijective swizzle (all our grids have nwg % 8 == 0)
  const int nwg = gridDim.x;
  const int bid = blockIdx.x;
  const int sw = (bid & 7) * (nwg >> 3) + (bid >> 3);
  const int mtiles = M / GBM;
  const int m0 = (sw % mtiles) * GBM;
  const int n0 = (sw / mtiles) * GBN;
  const int wm = w >> 1, wn = w & 1;       // 4 x 2 wave grid
  const int KT = K / GBK;
  const int ql = lane & 15, qh = (lane >> 4) * 16;
  f32x4 acc[4][4] = {};

  u16* const s0A = smem;
  // prologue: stage tiles 0,1 into slots 0,1 (6 loads each per wave, FIFO)
  stage_op<GBM>(A, K, m0, 0, s0A + 0 * SLOT_U16, w, lane);
  stage_op<GBN>(Bt, K, n0, 0, s0A + 0 * SLOT_U16 + GBM * GBK, w, lane);
  stage_op<GBM>(A, K, m0, 128, s0A + 1 * SLOT_U16, w, lane);
  stage_op<GBN>(Bt, K, n0, 128, s0A + 1 * SLOT_U16 + GBM * GBK, w, lane);
  asm volatile("s_waitcnt vmcnt(6)" ::: "memory");  // tile 0 landed (own 6 oldest)
  __builtin_amdgcn_s_barrier();
  asm volatile("" ::: "memory");

  for (int t = 0; t < KT; ++t) {
    const int s = t % 3;
    // prefetch tile t+2 into slot (t+2)%3 — that slot was consumed at iter t-1,
    // all waves are past its barrier: race-free.
    if (t + 2 < KT) {
      const int s2 = (t + 2) % 3;
      const int kb = (t + 2) * 128;
      stage_op<GBM>(A, K, m0, kb, s0A + s2 * SLOT_U16, w, lane);
      stage_op<GBN>(Bt, K, n0, kb, s0A + s2 * SLOT_U16 + GBM * GBK, w, lane);
    }
    const u16* sA = s0A + s * SLOT_U16;
    const u16* sB = sA + GBM * GBK;
#pragma unroll
    for (int kk = 0; kk < 2; ++kk) {
      bf16x8 af[4], bq[4];
      const int cb = kk * 64 + qh;
#pragma unroll
      for (int i = 0; i < 4; ++i) {
        const int row = wm * 64 + i * 16 + ql;
        const int byt = ((row << 7) + cb) ^ ((row & 7) << 4);
        af[i] = *(const bf16x8*)((const char*)sA + byt);
      }
#pragma unroll
      for (int j = 0; j < 4; ++j) {
        const int row = wn * 64 + j * 16 + ql;
        const int byt = ((row << 7) + cb) ^ ((row & 7) << 4);
        bq[j] = *(const bf16x8*)((const char*)sB + byt);
      }
      __builtin_amdgcn_s_setprio(1);
#pragma unroll
      for (int i = 0; i < 4; ++i)
#pragma unroll
        for (int j = 0; j < 4; ++j)
          acc[i][j] = __builtin_amdgcn_mfma_f32_16x16x32_bf16(af[i], bq[j], acc[i][j], 0, 0, 0);
      __builtin_amdgcn_s_setprio(0);
    }
    // counted wait: keep tile t+2's 6 loads in flight; drain only in the tail
    if (t < KT - 2) asm volatile("s_waitcnt vmcnt(6)" ::: "memory");
    else            asm volatile("s_waitcnt vmcnt(0)" ::: "memory");
    __builtin_amdgcn_s_barrier();
    asm volatile("" ::: "memory");
  }

  // epilogue
  const int rbase = (lane >> 4) * 4;
#pragma unroll
  for (int i = 0; i < 4; ++i) {
#pragma unroll
    for (int j = 0; j < 4; ++j) {
      const int grow0 = m0 + wm * 64 + i * 16 + rbase;
      const int gcol = n0 + wn * 64 + j * 16 + ql;
      if (EPI == 1) {
        const int b = grow0 >> 11, s4 = grow0 & (S_LEN - 1);
        const int h = gcol >> 6, dh = gcol & 63;
        uint2 o;
        o.x = (unsigned)f2bf(acc[i][j][0]) | ((unsigned)f2bf(acc[i][j][1]) << 16);
        o.y = (unsigned)f2bf(acc[i][j][2]) | ((unsigned)f2bf(acc[i][j][3]) << 16);
        *(uint2*)&obf[((((size_t)b * NHEAD + h) * DHEAD + dh) << 11) + s4] = o;
      } else {
#pragma unroll
        for (int r = 0; r < 4; ++r) {
          const int grow = grow0 + r;
          const float v = acc[i][j][r];
          if (EPI == 0) {
            obf[(size_t)grow * N + gcol] = f2bf(v);
          } else if (EPI == 2) {
            ofl[(size_t)grow * N + gcol] = xres[(size_t)grow * N + gcol] + v;
          } else if (EPI == 3) {
            ofl[(size_t)grow * N + gcol] += v;
          } else if (EPI == 4) {
            const float g = bf2f(gate[(size_t)grow * N + gcol]);
            const float sg = g / (1.f + __expf(-g));
            obf[(size_t)grow * N + gcol] = f2bf(sg * v);
          }
        }
      }
    }
  }
}

// ---------------- Flash attention (causal) ----------------
__global__ __launch_bounds__(256) void attn_kernel(
    const u16* __restrict__ q, const u16* __restrict__ k,
    const u16* __restrict__ vt, u16* __restrict__ o) {
  __shared__ u16 lK[64 * 64];
  __shared__ u16 lV[64 * 64];
  __shared__ u16 lP[4][16 * 64];
  const int tid = threadIdx.x, w = tid >> 6, lane = tid & 63;
  const int bx = blockIdx.x;
  const int bh = blockIdx.y;
  const int b = bh >> 5, h = bh & 31;
  const int q0 = bx * 64;
  const int ql = lane & 15;
  const int rbase = (lane >> 4) * 4;
  const int row_l = lane >> 3, kofs_l = (lane & 7) * 8;

  bf16x8 qf[2];
  {
    size_t tok = (size_t)b * S_LEN + q0 + w * 16 + ql;
#pragma unroll
    for (int kk = 0; kk < 2; ++kk)
      qf[kk] = *(const bf16x8*)&q[tok * D_MODEL + h * DHEAD + kk * 32 + (lane >> 4) * 8];
  }
  float mrow[4], lrow[4];
  f32x4 oacc[4] = {};
#pragma unroll
  for (int r = 0; r < 4; ++r) { mrow[r] = -1e30f; lrow[r] = 0.f; }

  for (int kt = 0; kt <= bx; ++kt) {
    const int s0 = kt * 64;
#pragma unroll
    for (int it = 0; it < 2; ++it) {
      int r = it * 32 + w * 8 + row_l;
      gload_lds16(&k[((size_t)b * S_LEN + s0 + r) * D_MODEL + h * DHEAD + kofs_l],
                  &lK[(it * 32 + w * 8) * 64]);
      gload_lds16(&vt[((size_t)bh * DHEAD + r) * S_LEN + s0 + kofs_l],
                  &lV[(it * 32 + w * 8) * 64]);
    }
    __syncthreads();
    f32x4 sc[4] = {};
#pragma unroll
    for (int kk = 0; kk < 2; ++kk) {
#pragma unroll
      for (int j = 0; j < 4; ++j) {
        bf16x8 bk = *(const bf16x8*)&lK[(j * 16 + ql) * 64 + kk * 32 + (lane >> 4) * 8];
        sc[j] = __builtin_amdgcn_mfma_f32_16x16x32_bf16(qf[kk], bk, sc[j], 0, 0, 0);
      }
    }
    const bool diag = (kt == bx);
#pragma unroll
    for (int j = 0; j < 4; ++j) {
#pragma unroll
      for (int r = 0; r < 4; ++r) {
        float v = sc[j][r] * 0.125f;
        if (diag) {
          int col = s0 + j * 16 + ql;
          int row = q0 + w * 16 + rbase + r;
          if (col > row) v = -1e30f;
        }
        sc[j][r] = v;
      }
    }
    float alpha[4];
#pragma unroll
    for (int r = 0; r < 4; ++r) {
      float mx = fmaxf(fmaxf(sc[0][r], sc[1][r]), fmaxf(sc[2][r], sc[3][r]));
#pragma unroll
      for (int d = 1; d < 16; d <<= 1) mx = fmaxf(mx, __shfl_xor(mx, d));
      float mnew = fmaxf(mrow[r], mx);
      alpha[r] = __expf(mrow[r] - mnew);
      mrow[r] = mnew;
      float rs = 0.f;
#pragma unroll
      for (int j = 0; j < 4; ++j) {
        float p = __expf(sc[j][r] - mnew);
        sc[j][r] = p;
        rs += p;
      }
#pragma unroll
      for (int d = 1; d < 16; d <<= 1) rs += __shfl_xor(rs, d);
      lrow[r] = lrow[r] * alpha[r] + rs;
    }
#pragma unroll
    for (int j = 0; j < 4; ++j)
#pragma unroll
      for (int r = 0; r < 4; ++r)
        oacc[j][r] *= alpha[r];
#pragma unroll
    for (int j = 0; j < 4; ++j)
#pragma unroll
      for (int r = 0; r < 4; ++r)
        lP[w][(rbase + r) * 64 + j * 16 + ql] = f2bf(sc[j][r]);
#pragma unroll
    for (int kk = 0; kk < 2; ++kk) {
      bf16x8 pa = *(const bf16x8*)&lP[w][ql * 64 + kk * 32 + (lane >> 4) * 8];
#pragma unroll
      for (int j = 0; j < 4; ++j) {
        bf16x8 bv = *(const bf16x8*)&lV[(j * 16 + ql) * 64 + kk * 32 + (lane >> 4) * 8];
        oacc[j] = __builtin_amdgcn_mfma_f32_16x16x32_bf16(pa, bv, oacc[j], 0, 0, 0);
      }
    }
    __syncthreads();
  }
#pragma unroll
  for (int r = 0; r < 4; ++r) {
    float inv = 1.f / lrow[r];
    size_t tok = (size_t)b * S_LEN + q0 + w * 16 + rbase + r;
#pragma unroll
    for (int j = 0; j < 4; ++j)
      o[tok * D_MODEL + h * DHEAD + j * 16 + ql] = f2bf(oacc[j][r] * inv);
  }
}

// ---------------- host ----------------
extern "C" void kernel_launch(void* const* d_in, const int* in_sizes, int n_in,
                              void* d_out, int out_size, void* d_ws, size_t ws_size,
                              hipStream_t stream) {
  (void)in_sizes; (void)n_in; (void)out_size; (void)ws_size;
  const float* x  = (const float*)d_in[0];
  const float* fc = (const float*)d_in[1];
  const float* fs = (const float*)d_in[2];
  const float* wq = (const float*)d_in[4];
  const float* wk = (const float*)d_in[5];
  const float* wv = (const float*)d_in[6];
  const float* wo = (const float*)d_in[7];
  const float* wg = (const float*)d_in[8];
  const float* wu = (const float*)d_in[9];
  const float* wd = (const float*)d_in[10];
  const float* n1 = (const float*)d_in[11];
  const float* n2 = (const float*)d_in[12];
  float* out = (float*)d_out;

  char* ws = (char*)d_ws;
  size_t off = 0;
  auto alloc = [&](size_t bytes) { void* p = ws + off; off += (bytes + 255) & ~(size_t)255; return p; };
  u16* wq_t = (u16*)alloc((size_t)D_MODEL * D_MODEL * 2);
  u16* wk_t = (u16*)alloc((size_t)D_MODEL * D_MODEL * 2);
  u16* wv_t = (u16*)alloc((size_t)D_MODEL * D_MODEL * 2);
  u16* wo_t = (u16*)alloc((size_t)D_MODEL * D_MODEL * 2);
  u16* wg_t = (u16*)alloc((size_t)D_MODEL * FF_DIM * 2);
  u16* wu_t = (u16*)alloc((size_t)D_MODEL * FF_DIM * 2);
  u16* wd_t = (u16*)alloc((size_t)FF_DIM * D_MODEL * 2);
  u16* hn   = (u16*)alloc((size_t)NTOK * D_MODEL * 2);
  u16* qb   = (u16*)alloc((size_t)NTOK * D_MODEL * 2);
  u16* kb   = (u16*)alloc((size_t)NTOK * D_MODEL * 2);
  u16* vtb  = (u16*)alloc((size_t)NTOK * D_MODEL * 2);
  u16* ao   = (u16*)alloc((size_t)NTOK * D_MODEL * 2);
  u16* gt   = (u16*)alloc((size_t)NTOK * FF_DIM * 2);

  // 1. weight convert+transpose
  wconv_kernel<<<dim3(32, 32), 256, 0, stream>>>(wq, wq_t, D_MODEL, D_MODEL);
  wconv_kernel<<<dim3(32, 32), 256, 0, stream>>>(wk, wk_t, D_MODEL, D_MODEL);
  wconv_kernel<<<dim3(32, 32), 256, 0, stream>>>(wv, wv_t, D_MODEL, D_MODEL);
  wconv_kernel<<<dim3(32, 32), 256, 0, stream>>>(wo, wo_t, D_MODEL, D_MODEL);
  wconv_kernel<<<dim3(FF_DIM / 64, 32), 256, 0, stream>>>(wg, wg_t, D_MODEL, FF_DIM);
  wconv_kernel<<<dim3(FF_DIM / 64, 32), 256, 0, stream>>>(wu, wu_t, D_MODEL, FF_DIM);
  wconv_kernel<<<dim3(32, FF_DIM / 64), 256, 0, stream>>>(wd, wd_t, FF_DIM, D_MODEL);
  // 2. rmsnorm1
  rmsnorm_kernel<<<NTOK, 256, 0, stream>>>(x, n1, hn);
  // 3. QKV  (grid = (M/256)*(N/128) = 256 blocks each)
  gemm3<0><<<256, 512, GEMM_LDS_BYTES, stream>>>(hn, wq_t, NTOK, D_MODEL, D_MODEL, qb, nullptr, nullptr, nullptr);
  gemm3<0><<<256, 512, GEMM_LDS_BYTES, stream>>>(hn, wk_t, NTOK, D_MODEL, D_MODEL, kb, nullptr, nullptr, nullptr);
  gemm3<1><<<256, 512, GEMM_LDS_BYTES, stream>>>(hn, wv_t, NTOK, D_MODEL, D_MODEL, vtb, nullptr, nullptr, nullptr);
  // 4. RoPE
  rope_kernel<<<dim3(NTOK * 1024 / 256, 2), 256, 0, stream>>>(qb, kb, fc, fs);
  // 5. attention
  attn_kernel<<<dim3(32, 64), 256, 0, stream>>>(qb, kb, vtb, ao);
  // 6. O proj + residual -> d_out
  gemm3<2><<<256, 512, GEMM_LDS_BYTES, stream>>>(ao, wo_t, NTOK, D_MODEL, D_MODEL, nullptr, out, x, nullptr);
  // 7. rmsnorm2
  rmsnorm_kernel<<<NTOK, 256, 0, stream>>>(out, n2, hn);
  // 8. gate (1024 blocks)
  gemm3<0><<<1024, 512, GEMM_LDS_BYTES, stream>>>(hn, wg_t, NTOK, FF_DIM, D_MODEL, gt, nullptr, nullptr, nullptr);
  // 9. up with fused silu(gate)*up
  gemm3<4><<<1024, 512, GEMM_LDS_BYTES, stream>>>(hn, wu_t, NTOK, FF_DIM, D_MODEL, gt, nullptr, nullptr, gt);
  // 10. down, += into d_out
  gemm3<3><<<256, 512, GEMM_LDS_BYTES, stream>>>(gt, wd_t, NTOK, D_MODEL, FF_DIM, nullptr, out, nullptr, nullptr);
}

// Round 3
// 939.732 us; speedup vs baseline: 1.3896x; 1.1238x over previous
//
#include <hip/hip_runtime.h>

typedef unsigned short u16;
typedef __attribute__((ext_vector_type(8))) short bf16x8;
typedef __attribute__((ext_vector_type(4))) float f32x4;

#define S_LEN 2048
#define D_MODEL 2048
#define NHEAD 32
#define DHEAD 64
#define FF_DIM 8192
#define NTOK 4096

// GEMM geometry: BM=256, BN=128, BK=64, 8 waves (4M x 2N), ring-3 LDS
#define GBM 256
#define GBN 128
#define GBK 64
#define SLOT_U16 (GBM * GBK + GBN * GBK)   // 24576 u16 = 48KB
#define GEMM_LDS_BYTES (3 * SLOT_U16 * 2)  // 144KB

__device__ __forceinline__ u16 f2bf(float f) {
  union { float f; unsigned u; } v; v.f = f;
  unsigned r = v.u + 0x7fffu + ((v.u >> 16) & 1u);
  return (u16)(r >> 16);
}
__device__ __forceinline__ float bf2f(u16 b) {
  union { unsigned u; float f; } v; v.u = ((unsigned)b) << 16;
  return v.f;
}
__device__ __forceinline__ void gload_lds16(const void* g, void* l) {
  __builtin_amdgcn_global_load_lds(
      (const __attribute__((address_space(1))) void*)g,
      (__attribute__((address_space(3))) void*)l, 16, 0, 0);
}

// ---------------- weight transpose + f32->bf16 convert ----------------
__global__ __launch_bounds__(256) void wconv_kernel(
    const float* __restrict__ in, u16* __restrict__ out, int Kd, int Nd) {
  __shared__ float tile[64][65];
  const int n0 = blockIdx.x * 64, k0 = blockIdx.y * 64;
  const int tid = threadIdx.x;
  const int r = tid >> 4, c4 = (tid & 15) * 4;
#pragma unroll
  for (int rr = 0; rr < 4; ++rr) {
    int kr = rr * 16 + r;
    float4 v = *(const float4*)&in[(size_t)(k0 + kr) * Nd + n0 + c4];
    tile[kr][c4 + 0] = v.x; tile[kr][c4 + 1] = v.y;
    tile[kr][c4 + 2] = v.z; tile[kr][c4 + 3] = v.w;
  }
  __syncthreads();
#pragma unroll
  for (int rr = 0; rr < 4; ++rr) {
    int nr = rr * 16 + r;
    uint2 o;
    o.x = (unsigned)f2bf(tile[c4 + 0][nr]) | ((unsigned)f2bf(tile[c4 + 1][nr]) << 16);
    o.y = (unsigned)f2bf(tile[c4 + 2][nr]) | ((unsigned)f2bf(tile[c4 + 3][nr]) << 16);
    *(uint2*)&out[(size_t)(n0 + nr) * Kd + k0 + c4] = o;
  }
}

// ---------------- RMSNorm: f32 in -> bf16 out ----------------
__global__ __launch_bounds__(256) void rmsnorm_kernel(
    const float* __restrict__ in, const float* __restrict__ wt, u16* __restrict__ out) {
  const int row = blockIdx.x;
  const int tid = threadIdx.x;
  const float* rp = in + (size_t)row * D_MODEL;
  float4 a = *(const float4*)&rp[tid * 8];
  float4 b = *(const float4*)&rp[tid * 8 + 4];
  float ss = a.x*a.x + a.y*a.y + a.z*a.z + a.w*a.w
           + b.x*b.x + b.y*b.y + b.z*b.z + b.w*b.w;
#pragma unroll
  for (int d = 1; d < 64; d <<= 1) ss += __shfl_xor(ss, d);
  __shared__ float red[4];
  if ((tid & 63) == 0) red[tid >> 6] = ss;
  __syncthreads();
  float tot = red[0] + red[1] + red[2] + red[3];
  float rms = rsqrtf(tot * (1.f / (float)D_MODEL) + 1e-6f);
  float4 wa = *(const float4*)&wt[tid * 8];
  float4 wb = *(const float4*)&wt[tid * 8 + 4];
  uint4 o;
  o.x = (unsigned)f2bf(a.x * rms * wa.x) | ((unsigned)f2bf(a.y * rms * wa.y) << 16);
  o.y = (unsigned)f2bf(a.z * rms * wa.z) | ((unsigned)f2bf(a.w * rms * wa.w) << 16);
  o.z = (unsigned)f2bf(b.x * rms * wb.x) | ((unsigned)f2bf(b.y * rms * wb.y) << 16);
  o.w = (unsigned)f2bf(b.z * rms * wb.z) | ((unsigned)f2bf(b.w * rms * wb.w) << 16);
  *(uint4*)&out[(size_t)row * D_MODEL + tid * 8] = o;
}

// ---------------- RoPE in-place on q,k (bf16) ----------------
__global__ __launch_bounds__(256) void rope_kernel(
    u16* __restrict__ q, u16* __restrict__ k,
    const float* __restrict__ fc, const float* __restrict__ fs) {
  const int idx = blockIdx.x * 256 + threadIdx.x;
  u16* t = blockIdx.y ? k : q;
  const int p = idx & 1023;
  const int i = p & 31;
  const int tok = idx >> 10;
  const int s = tok & (S_LEN - 1);
  unsigned u = ((unsigned*)t)[idx];
  float v0 = bf2f((u16)(u & 0xffff));
  float v1 = bf2f((u16)(u >> 16));
  float c = fc[s * 32 + i], sn = fs[s * 32 + i];
  float r0 = v0 * c - v1 * sn;
  float r1 = v0 * sn + v1 * c;
  ((unsigned*)t)[idx] = (unsigned)f2bf(r0) | ((unsigned)f2bf(r1) << 16);
}

// ---------------- GEMM staging (8 waves) ----------------
template <int RN>
__device__ __forceinline__ void stage_op(const u16* src, int Kelems,
                                         int row0, int ktbyte, u16* slot,
                                         int w, int lane) {
  constexpr int L = RN / 64;
#pragma unroll
  for (int l = 0; l < L; ++l) {
    const int dst = l * 8192 + w * 1024;
    const int dl = dst + lane * 16;
    const int srcb = dl ^ (((dl >> 7) & 7) << 4);
    const int row = srcb >> 7, colb = srcb & 127;
    gload_lds16((const char*)src + (size_t)(row0 + row) * Kelems * 2 + ktbyte + colb,
                (char*)slot + dst);
  }
}

// ---------------- GEMM core: ring-3, counted vmcnt, swizzled LDS ----------------
template <int EPI>
__global__ __launch_bounds__(512, 2) void gemm3(
    const u16* __restrict__ A, const u16* __restrict__ Bt,
    int M, int N, int K,
    u16* obf, float* ofl, const float* __restrict__ xres, const u16* gate) {
  extern __shared__ u16 smem[];
  const int tid = threadIdx.x;
  const int w = tid >> 6, lane = tid & 63;
  const int nwg = gridDim.x;
  const int bid = blockIdx.x;
  const int sw = (bid & 7) * (nwg >> 3) + (bid >> 3);
  const int mtiles = M / GBM;
  const int m0 = (sw % mtiles) * GBM;
  const int n0 = (sw / mtiles) * GBN;
  const int wm = w >> 1, wn = w & 1;
  const int KT = K / GBK;
  const int ql = lane & 15, qh = (lane >> 4) * 16;
  f32x4 acc[4][4] = {};

  u16* const s0A = smem;
  stage_op<GBM>(A, K, m0, 0, s0A + 0 * SLOT_U16, w, lane);
  stage_op<GBN>(Bt, K, n0, 0, s0A + 0 * SLOT_U16 + GBM * GBK, w, lane);
  stage_op<GBM>(A, K, m0, 128, s0A + 1 * SLOT_U16, w, lane);
  stage_op<GBN>(Bt, K, n0, 128, s0A + 1 * SLOT_U16 + GBM * GBK, w, lane);
  asm volatile("s_waitcnt vmcnt(6)" ::: "memory");
  __builtin_amdgcn_s_barrier();
  asm volatile("" ::: "memory");

  for (int t = 0; t < KT; ++t) {
    const int s = t % 3;
    if (t + 2 < KT) {
      const int s2 = (t + 2) % 3;
      const int kb = (t + 2) * 128;
      stage_op<GBM>(A, K, m0, kb, s0A + s2 * SLOT_U16, w, lane);
      stage_op<GBN>(Bt, K, n0, kb, s0A + s2 * SLOT_U16 + GBM * GBK, w, lane);
    }
    const u16* sA = s0A + s * SLOT_U16;
    const u16* sB = sA + GBM * GBK;
#pragma unroll
    for (int kk = 0; kk < 2; ++kk) {
      bf16x8 af[4], bq[4];
      const int cb = kk * 64 + qh;
#pragma unroll
      for (int i = 0; i < 4; ++i) {
        const int row = wm * 64 + i * 16 + ql;
        const int byt = ((row << 7) + cb) ^ ((row & 7) << 4);
        af[i] = *(const bf16x8*)((const char*)sA + byt);
      }
#pragma unroll
      for (int j = 0; j < 4; ++j) {
        const int row = wn * 64 + j * 16 + ql;
        const int byt = ((row << 7) + cb) ^ ((row & 7) << 4);
        bq[j] = *(const bf16x8*)((const char*)sB + byt);
      }
      __builtin_amdgcn_s_setprio(1);
#pragma unroll
      for (int i = 0; i < 4; ++i)
#pragma unroll
        for (int j = 0; j < 4; ++j)
          acc[i][j] = __builtin_amdgcn_mfma_f32_16x16x32_bf16(af[i], bq[j], acc[i][j], 0, 0, 0);
      __builtin_amdgcn_s_setprio(0);
    }
    if (t < KT - 2) asm volatile("s_waitcnt vmcnt(6)" ::: "memory");
    else            asm volatile("s_waitcnt vmcnt(0)" ::: "memory");
    __builtin_amdgcn_s_barrier();
    asm volatile("" ::: "memory");
  }

  const int rbase = (lane >> 4) * 4;
#pragma unroll
  for (int i = 0; i < 4; ++i) {
#pragma unroll
    for (int j = 0; j < 4; ++j) {
      const int grow0 = m0 + wm * 64 + i * 16 + rbase;
      const int gcol = n0 + wn * 64 + j * 16 + ql;
      if (EPI == 1) {
        const int b = grow0 >> 11, s4 = grow0 & (S_LEN - 1);
        const int h = gcol >> 6, dh = gcol & 63;
        uint2 o;
        o.x = (unsigned)f2bf(acc[i][j][0]) | ((unsigned)f2bf(acc[i][j][1]) << 16);
        o.y = (unsigned)f2bf(acc[i][j][2]) | ((unsigned)f2bf(acc[i][j][3]) << 16);
        *(uint2*)&obf[((((size_t)b * NHEAD + h) * DHEAD + dh) << 11) + s4] = o;
      } else {
#pragma unroll
        for (int r = 0; r < 4; ++r) {
          const int grow = grow0 + r;
          const float v = acc[i][j][r];
          if (EPI == 0) {
            obf[(size_t)grow * N + gcol] = f2bf(v);
          } else if (EPI == 2) {
            ofl[(size_t)grow * N + gcol] = xres[(size_t)grow * N + gcol] + v;
          } else if (EPI == 3) {
            ofl[(size_t)grow * N + gcol] += v;
          } else if (EPI == 4) {
            const float g = bf2f(gate[(size_t)grow * N + gcol]);
            const float sg = g / (1.f + __expf(-g));
            obf[(size_t)grow * N + gcol] = f2bf(sg * v);
          }
        }
      }
    }
  }
}

// ---------------- Flash attention (causal), swapped-QK^T, swizzled, ring-2 ----------------
// q,k: [NTOK][D_MODEL] bf16 (post-rope); vt: [B*NHEAD][DHEAD][S_LEN] bf16
// QBLK=128 (4 waves x 32 rows), KVBLK=64.
__global__ __launch_bounds__(256) void attn_kernel(
    const u16* __restrict__ q, const u16* __restrict__ k,
    const u16* __restrict__ vt, u16* __restrict__ o) {
  __shared__ u16 lKV[2][128 * 64];   // per slot: rows 0-63 = K, rows 64-127 = V^T (d rows)
  __shared__ u16 lP[4][32 * 64];     // per wave: 32 q-rows x 64 kv
  const int tid = threadIdx.x, w = tid >> 6, lane = tid & 63;
  const int ql = lane & 15, qh16 = (lane >> 4) * 16, rbase = (lane >> 4) * 4;
  const int bx = (int)gridDim.x - 1 - (int)blockIdx.x;   // heavy tiles first
  const int bh = blockIdx.y, b = bh >> 5, h = bh & 31;
  const int q0 = bx * 128;
  const int nt = 2 * bx + 2;
  const char* kbase = (const char*)(k + ((size_t)b * S_LEN) * D_MODEL + h * DHEAD);
  const char* vbase = (const char*)(vt + (size_t)bh * DHEAD * S_LEN);

  // Q fragments, pre-scaled by 1/sqrt(Dh)=0.125 (exact in bf16)
  bf16x8 qf[2][2];
#pragma unroll
  for (int i = 0; i < 2; ++i) {
    const size_t tok = (size_t)b * S_LEN + q0 + w * 32 + i * 16 + ql;
#pragma unroll
    for (int kk = 0; kk < 2; ++kk) {
      bf16x8 v = *(const bf16x8*)&q[tok * D_MODEL + h * DHEAD + kk * 32 + (lane >> 4) * 8];
#pragma unroll
      for (int e = 0; e < 8; ++e) v[e] = (short)f2bf(bf2f((u16)v[e]) * 0.125f);
      qf[i][kk] = v;
    }
  }

  float m[2] = {-1e30f, -1e30f}, l[2] = {0.f, 0.f};
  f32x4 oacc[2][4] = {};

  auto stage = [&](int kt, int slot) {
    const int s0 = kt * 64;
#pragma unroll
    for (int lo = 0; lo < 2; ++lo) {
      const int dst = lo * 4096 + w * 1024;
      const int dl = dst + lane * 16;
      const int srcb = dl ^ (((dl >> 7) & 7) << 4);
      const int row = srcb >> 7, colb = srcb & 127;
      gload_lds16(kbase + (size_t)(s0 + row) * (D_MODEL * 2) + colb,
                  (char*)&lKV[slot][0] + dst);
    }
#pragma unroll
    for (int lo = 0; lo < 2; ++lo) {
      const int dst = lo * 4096 + w * 1024;
      const int dl = dst + lane * 16;
      const int srcb = dl ^ (((dl >> 7) & 7) << 4);
      const int row = srcb >> 7, colb = srcb & 127;
      gload_lds16(vbase + (size_t)row * (S_LEN * 2) + (size_t)s0 * 2 + colb,
                  (char*)&lKV[slot][64 * 64] + dst);
    }
  };

  stage(0, 0);
  for (int kt = 0; kt < nt; ++kt) {
    if (kt + 1 < nt) {
      stage(kt + 1, (kt + 1) & 1);
      asm volatile("s_waitcnt vmcnt(4)" ::: "memory");
    } else {
      asm volatile("s_waitcnt vmcnt(0)" ::: "memory");
    }
    __builtin_amdgcn_s_barrier();
    asm volatile("" ::: "memory");

    const u16* sK = &lKV[kt & 1][0];
    const u16* sV = &lKV[kt & 1][64 * 64];
    const int s0 = kt * 64;

    // swapped QK^T: scT[i][j] = K_j · Q_i^T -> lane holds q=lane&15, kv in regs
    f32x4 scT[2][4] = {};
#pragma unroll
    for (int kk = 0; kk < 2; ++kk) {
#pragma unroll
      for (int j = 0; j < 4; ++j) {
        const int row = j * 16 + ql;
        bf16x8 kf = *(const bf16x8*)((const char*)sK +
                      (((row << 7) + kk * 64 + qh16) ^ ((row & 7) << 4)));
#pragma unroll
        for (int i = 0; i < 2; ++i)
          scT[i][j] = __builtin_amdgcn_mfma_f32_16x16x32_bf16(kf, qf[i][kk], scT[i][j], 0, 0, 0);
      }
    }
    const bool diag = (s0 + 63 > q0);
#pragma unroll
    for (int i = 0; i < 2; ++i) {
      const int qrow = q0 + w * 32 + i * 16 + ql;
      if (diag) {
#pragma unroll
        for (int j = 0; j < 4; ++j)
#pragma unroll
          for (int r = 0; r < 4; ++r)
            if (s0 + j * 16 + rbase + r > qrow) scT[i][j][r] = -1e30f;
      }
      float mx = scT[i][0][0];
#pragma unroll
      for (int j = 0; j < 4; ++j)
#pragma unroll
        for (int r = 0; r < 4; ++r) mx = fmaxf(mx, scT[i][j][r]);
      mx = fmaxf(mx, __shfl_xor(mx, 16));
      mx = fmaxf(mx, __shfl_xor(mx, 32));
      const float mnew = fmaxf(m[i], mx);
      const float alpha = __expf(m[i] - mnew);
      m[i] = mnew;
      float rs = 0.f;
#pragma unroll
      for (int j = 0; j < 4; ++j)
#pragma unroll
        for (int r = 0; r < 4; ++r) {
          const float p = __expf(scT[i][j][r] - mnew);
          scT[i][j][r] = p;
          rs += p;
        }
      rs += __shfl_xor(rs, 16);
      rs += __shfl_xor(rs, 32);
      l[i] = l[i] * alpha + rs;
      // rescale O-acc (its rows are rbase+rr) with alpha from lane rbase+rr
#pragma unroll
      for (int rr = 0; rr < 4; ++rr) {
        const float ar = __shfl(alpha, rbase + rr);
#pragma unroll
        for (int j = 0; j < 4; ++j) oacc[i][j][rr] *= ar;
      }
      // P -> LDS (swizzled, packed u32 of 2 consecutive kv)
      const int prow = i * 16 + ql;
      const int pb = prow << 7;
      const int swz = (prow & 7) << 4;
#pragma unroll
      for (int j = 0; j < 4; ++j) {
#pragma unroll
        for (int rp = 0; rp < 2; ++rp) {
          const int col = j * 16 + rbase + rp * 2;
          unsigned pk = (unsigned)f2bf(scT[i][j][rp * 2]) |
                        ((unsigned)f2bf(scT[i][j][rp * 2 + 1]) << 16);
          *(unsigned*)((char*)lP[w] + ((pb + col * 2) ^ swz)) = pk;
        }
      }
    }
    // PV: oacc[i][j] += P_i · V_j
#pragma unroll
    for (int i = 0; i < 2; ++i) {
      const int arow = i * 16 + ql;
#pragma unroll
      for (int kk = 0; kk < 2; ++kk) {
        bf16x8 pa = *(const bf16x8*)((const char*)lP[w] +
                      (((arow << 7) + kk * 64 + qh16) ^ ((arow & 7) << 4)));
#pragma unroll
        for (int j = 0; j < 4; ++j) {
          const int vrow = j * 16 + ql;
          bf16x8 bv = *(const bf16x8*)((const char*)sV +
                        (((vrow << 7) + kk * 64 + qh16) ^ ((vrow & 7) << 4)));
          oacc[i][j] = __builtin_amdgcn_mfma_f32_16x16x32_bf16(pa, bv, oacc[i][j], 0, 0, 0);
        }
      }
    }
    __builtin_amdgcn_s_barrier();
    asm volatile("" ::: "memory");
  }
#pragma unroll
  for (int i = 0; i < 2; ++i) {
#pragma unroll
    for (int rr = 0; rr < 4; ++rr) {
      const float linv = 1.f / __shfl(l[i], rbase + rr);
      const size_t tok = (size_t)b * S_LEN + q0 + w * 32 + i * 16 + rbase + rr;
#pragma unroll
      for (int j = 0; j < 4; ++j)
        o[tok * D_MODEL + h * DHEAD + j * 16 + ql] = f2bf(oacc[i][j][rr] * linv);
    }
  }
}

// ---------------- host ----------------
extern "C" void kernel_launch(void* const* d_in, const int* in_sizes, int n_in,
                              void* d_out, int out_size, void* d_ws, size_t ws_size,
                              hipStream_t stream) {
  (void)in_sizes; (void)n_in; (void)out_size; (void)ws_size;
  const float* x  = (const float*)d_in[0];
  const float* fc = (const float*)d_in[1];
  const float* fs = (const float*)d_in[2];
  const float* wq = (const float*)d_in[4];
  const float* wk = (const float*)d_in[5];
  const float* wv = (const float*)d_in[6];
  const float* wo = (const float*)d_in[7];
  const float* wg = (const float*)d_in[8];
  const float* wu = (const float*)d_in[9];
  const float* wd = (const float*)d_in[10];
  const float* n1 = (const float*)d_in[11];
  const float* n2 = (const float*)d_in[12];
  float* out = (float*)d_out;

  char* ws = (char*)d_ws;
  size_t off = 0;
  auto alloc = [&](size_t bytes) { void* p = ws + off; off += (bytes + 255) & ~(size_t)255; return p; };
  u16* wq_t = (u16*)alloc((size_t)D_MODEL * D_MODEL * 2);
  u16* wk_t = (u16*)alloc((size_t)D_MODEL * D_MODEL * 2);
  u16* wv_t = (u16*)alloc((size_t)D_MODEL * D_MODEL * 2);
  u16* wo_t = (u16*)alloc((size_t)D_MODEL * D_MODEL * 2);
  u16* wg_t = (u16*)alloc((size_t)D_MODEL * FF_DIM * 2);
  u16* wu_t = (u16*)alloc((size_t)D_MODEL * FF_DIM * 2);
  u16* wd_t = (u16*)alloc((size_t)FF_DIM * D_MODEL * 2);
  u16* hn   = (u16*)alloc((size_t)NTOK * D_MODEL * 2);
  u16* qb   = (u16*)alloc((size_t)NTOK * D_MODEL * 2);
  u16* kb   = (u16*)alloc((size_t)NTOK * D_MODEL * 2);
  u16* vtb  = (u16*)alloc((size_t)NTOK * D_MODEL * 2);
  u16* ao   = (u16*)alloc((size_t)NTOK * D_MODEL * 2);
  u16* gt   = (u16*)alloc((size_t)NTOK * FF_DIM * 2);

  wconv_kernel<<<dim3(32, 32), 256, 0, stream>>>(wq, wq_t, D_MODEL, D_MODEL);
  wconv_kernel<<<dim3(32, 32), 256, 0, stream>>>(wk, wk_t, D_MODEL, D_MODEL);
  wconv_kernel<<<dim3(32, 32), 256, 0, stream>>>(wv, wv_t, D_MODEL, D_MODEL);
  wconv_kernel<<<dim3(32, 32), 256, 0, stream>>>(wo, wo_t, D_MODEL, D_MODEL);
  wconv_kernel<<<dim3(FF_DIM / 64, 32), 256, 0, stream>>>(wg, wg_t, D_MODEL, FF_DIM);
  wconv_kernel<<<dim3(FF_DIM / 64, 32), 256, 0, stream>>>(wu, wu_t, D_MODEL, FF_DIM);
  wconv_kernel<<<dim3(32, FF_DIM / 64), 256, 0, stream>>>(wd, wd_t, FF_DIM, D_MODEL);
  rmsnorm_kernel<<<NTOK, 256, 0, stream>>>(x, n1, hn);
  gemm3<0><<<256, 512, GEMM_LDS_BYTES, stream>>>(hn, wq_t, NTOK, D_MODEL, D_MODEL, qb, nullptr, nullptr, nullptr);
  gemm3<0><<<256, 512, GEMM_LDS_BYTES, stream>>>(hn, wk_t, NTOK, D_MODEL, D_MODEL, kb, nullptr, nullptr, nullptr);
  gemm3<1><<<256, 512, GEMM_LDS_BYTES, stream>>>(hn, wv_t, NTOK, D_MODEL, D_MODEL, vtb, nullptr, nullptr, nullptr);
  rope_kernel<<<dim3(NTOK * 1024 / 256, 2), 256, 0, stream>>>(qb, kb, fc, fs);
  attn_kernel<<<dim3(16, 64), 256, 0, stream>>>(qb, kb, vtb, ao);
  gemm3<2><<<256, 512, GEMM_LDS_BYTES, stream>>>(ao, wo_t, NTOK, D_MODEL, D_MODEL, nullptr, out, x, nullptr);
  rmsnorm_kernel<<<NTOK, 256, 0, stream>>>(out, n2, hn);
  gemm3<0><<<1024, 512, GEMM_LDS_BYTES, stream>>>(hn, wg_t, NTOK, FF_DIM, D_MODEL, gt, nullptr, nullptr, nullptr);
  gemm3<4><<<1024, 512, GEMM_LDS_BYTES, stream>>>(hn, wu_t, NTOK, FF_DIM, D_MODEL, gt, nullptr, nullptr, gt);
  gemm3<3><<<256, 512, GEMM_LDS_BYTES, stream>>>(gt, wd_t, NTOK, D_MODEL, FF_DIM, nullptr, out, nullptr, nullptr);
}